// Round 10
// baseline (575.190 us; speedup 1.0000x reference)
//
#include <hip/hip_runtime.h>
#include <hip/hip_bf16.h>

// B=64, C=1, H=W=1024, KS=16, F=128, OUT=10, L=4096, K=256
#define B_    64
#define F_    128
#define L_    4096
#define K_    256
#define OUT_  10
#define HW_   (1024 * 1024)
#define WIMG_ 1024
#define NL    4               // consecutive l's per block (same hb row)
#define NBLK  (L_ / NL)       // 1024 blocks

typedef __attribute__((ext_vector_type(8))) short bf16x8;   // MFMA A/B frag
typedef __attribute__((ext_vector_type(4))) float f32x4;    // MFMA C/D frag

static __device__ __forceinline__ unsigned short f2bf(float f) {
    return __builtin_bit_cast(unsigned short, __float2bfloat16(f));
}
static __device__ __forceinline__ float bf2f(unsigned short h) {
    unsigned int i = ((unsigned int)h) << 16;
    return __builtin_bit_cast(float, i);
}
static __device__ __forceinline__ ushort4 c4u(float4 v) {
    return make_ushort4(f2bf(v.x), f2bf(v.y), f2bf(v.z), f2bf(v.w));
}

// ---------------------------------------------------------------------------
// R10: NL=4 l-chunk, 1024 threads = 16 waves, 64KB STATIC LDS (R8-proven size).
//  - x: one load instr spans 4 adjacent patches -> 4 x 256B dense segments.
//       All 4 l's held in regs as bf16 (16 ushort4 = 32 VGPR), staged to
//       xs[64][256] (32KB) when their l comes up (lane's il == l_i).
//  - w: one load instr = one full (f,l) row = 1KB contiguous (64 lanes x 16B).
//       Staged to wm[64][256] (32KB) per f-half phase; prefetched one phase
//       ahead into regs.
//  - wave (bq = b-quarter of 16, wf = f-group of 16): 8 MFMA per phase.
//  - epilogue: ym (bf16, overlays wm) -> decoder map (tx5:32 b-pairs x
//    tyf:16 f-octets x oh:2 o-halves) -> part[2][5] -> red[16][64][10] (40KB).
// ---------------------------------------------------------------------------
__global__ __launch_bounds__(1024)
void lcn_main(const float* __restrict__ x, const float* __restrict__ wgt,
              const float* __restrict__ bias, const float* __restrict__ dec_w,
              float* __restrict__ ws) {
    const int blk = blockIdx.x;
    const int hb  = blk >> 4;           // 0..63
    const int wq  = blk & 15;           // 4-patch chunk within image row
    const int l0  = hb * 64 + wq * NL;
    const int t    = threadIdx.x;
    const int lane = t & 63;
    const int w    = t >> 6;            // wave 0..15
    const int ln15 = lane & 15;
    const int kg   = lane >> 4;         // 0..3
    const int bq   = w >> 2;            // b-quarter (16 b's)
    const int wf   = w & 3;             // f-group within 64-f half
    const int fb   = wf * 16 + ln15;    // local f in half (0..63)
    const int bln  = bq * 16 + ln15;    // this lane's A-frag b row

    __shared__ union {
        struct { unsigned short xs[B_ * K_]; unsigned short wm[64 * K_]; } s; // 64KB
        float red[16][B_][OUT_];        // 40KB (after l-loop)
    } u;

    // ---- x loads: each instr = 4 x 256B dense segments (4 adjacent patches)
    const int xr  = lane >> 4;          // patch row-sub 0..3
    const int c4  = lane & 15;          // float4 slot across the 4 patches
    const int il  = c4 >> 2;            // which patch this lane's data is
    const int cin = (c4 & 3) * 4;       // col within patch
    ushort4 xv[16];                     // bf16: 4 b's x 4 row-groups
    {
        const float* xb = x + (size_t)(hb * 16 + xr) * WIMG_ + wq * 64 + c4 * 4;
        #pragma unroll
        for (int i = 0; i < 4; ++i)
            #pragma unroll
            for (int rg = 0; rg < 4; ++rg)
                xv[i * 4 + rg] = c4u(*reinterpret_cast<const float4*>(
                    xb + (size_t)(w * 4 + i) * HW_ + (size_t)rg * 4 * WIMG_));
    }

    float4 wg[4];
    auto WLOAD = [&](int l, int fh) {   // 1KB contiguous per instruction
        #pragma unroll
        for (int i = 0; i < 4; ++i) {
            const int f = fh * 64 + w * 4 + i;
            wg[i] = *reinterpret_cast<const float4*>(
                wgt + ((size_t)f * L_ + l) * K_ + lane * 4);
        }
    };
    auto WSTORE = [&]() {               // regs -> wm (swizzled)
        #pragma unroll
        for (int i = 0; i < 4; ++i) {
            const int fl = w * 4 + i;
            *reinterpret_cast<ushort4*>(
                &u.s.wm[fl * K_ + ((lane * 4) ^ ((fl & 7) << 3))]) = c4u(wg[i]);
        }
    };
    auto XSTORE = [&](int which) {      // lane's patch -> xs (if its turn)
        if (il == which) {
            #pragma unroll
            for (int i = 0; i < 4; ++i)
                #pragma unroll
                for (int rg = 0; rg < 4; ++rg) {
                    const int b = w * 4 + i;
                    const int k = (rg * 4 + xr) * 16 + cin;
                    *reinterpret_cast<ushort4*>(
                        &u.s.xs[b * K_ + (k ^ ((b & 7) << 3))]) = xv[i * 4 + rg];
                }
        }
    };

    // bias preload for all 4 l's (scattered dwords, done once up front)
    float bv0a[NL], bv1a[NL];
    #pragma unroll
    for (int i = 0; i < NL; ++i) {
        bv0a[i] = bias[(size_t)fb * L_ + l0 + i];
        bv1a[i] = bias[(size_t)(64 + fb) * L_ + l0 + i];
    }

    WLOAD(l0, 0);
    XSTORE(0);

    // decoder map: 32 b-pairs x 16 f-octets x 2 o-halves = 1024 (exact cover)
    const int tx5 = t & 31;             // b-pair: rows db0, db0+1
    const int tyf = (t >> 5) & 15;      // f-octet: df0..df0+7
    const int oh  = t >> 9;             // o-half
    const int db0 = tx5 * 2, df0 = tyf * 8;

    unsigned short* ym = u.s.wm;        // [64][136] bf16, overlays wm after D

    float part[2][5];
    #pragma unroll
    for (int bi = 0; bi < 2; ++bi)
        #pragma unroll
        for (int oo = 0; oo < 5; ++oo) part[bi][oo] = 0.f;

    for (int l_i = 0; l_i < NL; ++l_i) {
        const int l = l0 + l_i;
        f32x4 acc0 = (f32x4){0.f, 0.f, 0.f, 0.f};
        f32x4 acc1 = (f32x4){0.f, 0.f, 0.f, 0.f};

        WSTORE();                        // wm <- (l, f-half 0)
        WLOAD(l, 1);                     // prefetch f-half 1
        __syncthreads();                 // A: xs(l) + wm(fh0) ready

        #pragma unroll
        for (int ks = 0; ks < 8; ++ks) {
            const int kb = ks * 32 + kg * 8;
            const bf16x8 a = *reinterpret_cast<const bf16x8*>(
                &u.s.xs[bln * K_ + (kb ^ ((bln & 7) << 3))]);
            const bf16x8 bw = *reinterpret_cast<const bf16x8*>(
                &u.s.wm[fb * K_ + (kb ^ ((fb & 7) << 3))]);
            acc0 = __builtin_amdgcn_mfma_f32_16x16x32_bf16(a, bw, acc0, 0, 0, 0);
        }
        __syncthreads();                 // B: wm(fh0) reads done

        WSTORE();                        // wm <- (l, f-half 1)
        if (l_i < NL - 1) WLOAD(l + 1, 0);
        __syncthreads();                 // C: wm(fh1) ready

        #pragma unroll
        for (int ks = 0; ks < 8; ++ks) {
            const int kb = ks * 32 + kg * 8;
            const bf16x8 a = *reinterpret_cast<const bf16x8*>(
                &u.s.xs[bln * K_ + (kb ^ ((bln & 7) << 3))]);
            const bf16x8 bw = *reinterpret_cast<const bf16x8*>(
                &u.s.wm[fb * K_ + (kb ^ ((fb & 7) << 3))]);
            acc1 = __builtin_amdgcn_mfma_f32_16x16x32_bf16(a, bw, acc1, 0, 0, 0);
        }
        __syncthreads();                 // D: wm + xs reads done

        // ---- epilogue: bias + ReLU -> ym (overlays wm; safe after D) ----
        #pragma unroll
        for (int r = 0; r < 4; ++r) {
            const int b = bq * 16 + kg * 4 + r;   // C/D: row=(lane>>4)*4+reg
            ym[b * 136 + fb]      = f2bf(fmaxf(acc0[r] + bv0a[l_i], 0.f));
            ym[b * 136 + 64 + fb] = f2bf(fmaxf(acc1[r] + bv1a[l_i], 0.f));
        }
        if (l_i < NL - 1) XSTORE(l_i + 1);        // xs free after D
        __syncthreads();                 // E: ym + xs(l+1) ready

        // ---- fused decoder: accumulate part over this l ----
        bf16x8 yb0 = *reinterpret_cast<const bf16x8*>(&ym[(db0 + 0) * 136 + df0]);
        bf16x8 yb1 = *reinterpret_cast<const bf16x8*>(&ym[(db0 + 1) * 136 + df0]);
        #pragma unroll
        for (int fj = 0; fj < 8; ++fj) {
            const float y0 = bf2f((unsigned short)yb0[fj]);
            const float y1 = bf2f((unsigned short)yb1[fj]);
            #pragma unroll
            for (int oo = 0; oo < 5; ++oo) {
                const int o = oh * 5 + oo;
                const float dw = dec_w[(size_t)o * ((size_t)F_ * L_)
                                       + (size_t)(df0 + fj) * L_ + l];
                part[0][oo] = fmaf(y0, dw, part[0][oo]);
                part[1][oo] = fmaf(y1, dw, part[1][oo]);
            }
        }
        __syncthreads();                 // F: ym reads done (next WSTORE safe)
    }

    // ---- block reduction: red[16][64][10] overlays union (all LDS dead) ----
    #pragma unroll
    for (int bi = 0; bi < 2; ++bi)
        #pragma unroll
        for (int oo = 0; oo < 5; ++oo)
            u.red[tyf][db0 + bi][oh * 5 + oo] = part[bi][oo];
    __syncthreads();

    if (t < B_ * OUT_) {
        const int b = t / OUT_;
        const int o = t - b * OUT_;
        float s = 0.f;
        #pragma unroll
        for (int g = 0; g < 16; ++g) s += u.red[g][b][o];
        ws[((size_t)b * NBLK + blk) * OUT_ + o] = s;
    }
}

// ---------------------------------------------------------------------------
// Kernel B: reduce ws[b][1024][10] over chunks, add dec_b.
// ---------------------------------------------------------------------------
__global__ __launch_bounds__(640)
void lcn_reduce(const float* __restrict__ ws, const float* __restrict__ dec_b,
                float* __restrict__ out) {
    const int b = blockIdx.x;
    const int j = threadIdx.x;            // 0..639
    const float* base = ws + (size_t)b * (NBLK * OUT_);

    float s = 0.f;
    #pragma unroll 4
    for (int i = 0; i < (NBLK * OUT_) / 640; ++i)   // 16
        s += base[j + i * 640];

    __shared__ float lds[640];
    lds[j] = s;
    __syncthreads();

    if (j < OUT_) {
        float tot = dec_b[j];
        #pragma unroll
        for (int lc = 0; lc < 64; ++lc) tot += lds[lc * OUT_ + j];
        out[b * OUT_ + j] = tot;
    }
}

extern "C" void kernel_launch(void* const* d_in, const int* in_sizes, int n_in,
                              void* d_out, int out_size, void* d_ws, size_t ws_size,
                              hipStream_t stream) {
    const float* x     = (const float*)d_in[0];
    const float* wgt   = (const float*)d_in[1];
    const float* bias  = (const float*)d_in[2];
    const float* dec_w = (const float*)d_in[3];
    const float* dec_b = (const float*)d_in[4];
    float* out = (float*)d_out;
    float* wsf = (float*)d_ws;   // 64*1024*10*4 = 2.62 MB

    lcn_main<<<dim3(NBLK), dim3(1024), 0, stream>>>(x, wgt, bias, dec_w, wsf);
    lcn_reduce<<<dim3(B_), dim3(640), 0, stream>>>(wsf, dec_b, out);
}